// Round 16
// baseline (66.360 us; speedup 1.0000x reference)
//
#include <hip/hip_runtime.h>
#include <hip/hip_bf16.h>

// out[b,s,c] = x[b,s,:] @ W, W[r][c] = kernel[(r%512)*4096 + c]
// xr[m][r'] = sum_{i<8} x[m][r'+512i]  (M=8192, K'=512)
// INT8: xq = clamp(round(xr*8),-127,127); btq = kernel^T i8; out = acc*0.125f.
// Round 16: R11 exactly + NONTEMPORAL full-line dwordx4 C stores (C is
// write-once; keep it out of L2 so btq stays L2-resident for stageB).
// R4's NT failure was 4B scatter (sub-sector RMW); these are wave-complete
// 128B lines -> NT-safe.

#define M_TOT   8192
#define N_TOT   4096
#define K_RED   512
#define K_FULL  4096
#define NSTEPS  16          // 512-col stripe / 32

typedef __attribute__((ext_vector_type(4))) int   i32x4;
typedef __attribute__((ext_vector_type(4))) float f32x4;

// ---------------------------------------------------------------------------
// Prep (validated R5): blocks [0,4096): xq = i8 of 8-way reduced x (scale 8);
// blocks [4096,4608): btq[c][r'] = i8(kernel[r'*4096 + c]).
// ---------------------------------------------------------------------------
__global__ __launch_bounds__(256) void prep(const float* __restrict__ x,
                                            const int* __restrict__ kin,
                                            char* __restrict__ xq,
                                            char* __restrict__ btq) {
    __shared__ char tile[64][68];
    if (blockIdx.x < 4096) {
        const int row = blockIdx.x * 2 + (threadIdx.x >> 7);
        const int t2  = threadIdx.x & 127;
        const float* xp = x + (size_t)row * K_FULL + t2 * 4;
        float a0 = 0.f, a1 = 0.f, a2 = 0.f, a3 = 0.f;
#pragma unroll
        for (int i = 0; i < 8; ++i) {
            float4 v = *reinterpret_cast<const float4*>(xp + (size_t)i * K_RED);
            a0 += v.x; a1 += v.y; a2 += v.z; a3 += v.w;
        }
        int q0 = (int)rintf(a0 * 8.f), q1 = (int)rintf(a1 * 8.f);
        int q2 = (int)rintf(a2 * 8.f), q3 = (int)rintf(a3 * 8.f);
        q0 = min(127, max(-127, q0)); q1 = min(127, max(-127, q1));
        q2 = min(127, max(-127, q2)); q3 = min(127, max(-127, q3));
        int packed = (q0 & 0xFF) | ((q1 & 0xFF) << 8) | ((q2 & 0xFF) << 16)
                   | ((q3 & 0xFF) << 24);
        *reinterpret_cast<int*>(xq + (size_t)row * K_RED + t2 * 4) = packed;
    } else {
        const int b  = blockIdx.x - 4096;        // 0..511
        const int c0 = (b & 63) * 64;
        const int r0 = (b >> 6) * 64;
        const int tx = threadIdx.x & 63;
        const int ty = threadIdx.x >> 6;         // 0..3
#pragma unroll
        for (int rr = 0; rr < 64; rr += 4) {
            int r = r0 + rr + ty;
            tile[rr + ty][tx] = (char)kin[(size_t)r * N_TOT + c0 + tx];
        }
        __syncthreads();
        const int q  = tx & 15;                  // r'-quad (r' = q*4+j)
        const int ch = tx >> 4;                  // 0..3
#pragma unroll
        for (int i = 0; i < 4; ++i) {
            const int cl = i * 16 + ty * 4 + ch; // column offset 0..63
            int p = (tile[q * 4 + 0][cl] & 0xFF)
                  | ((tile[q * 4 + 1][cl] & 0xFF) << 8)
                  | ((tile[q * 4 + 2][cl] & 0xFF) << 16)
                  | ((tile[q * 4 + 3][cl] & 0xFF) << 24);
            *reinterpret_cast<int*>(btq + (size_t)(c0 + cl) * K_RED + r0 + q * 4) = p;
        }
    }
}

// ---------------------------------------------------------------------------
// A-resident streamed GEMM v8 (== R11 + NT stores).
// Grid 512 = 64 M-tiles(128 rows) x 8 N-stripes(512 cols). 512 thr = 8 waves;
// wave w owns rows w*16..w*16+15, all 32 cols of each step.
// LDS = 2 x 16KB B dbuf; swizzle both sides: kb ^= (col&7)<<4.
// Swapped-operand D = mfma(bf, af): lane -> m=l15, n=lhi*4+reg.
// ---------------------------------------------------------------------------
__global__ __launch_bounds__(512, 4) void gemm_as8(const char* __restrict__ A,
                                                   const char* __restrict__ Bt,
                                                   float* __restrict__ C) {
    __shared__ char smem[32768];     // 2 x 16KB B double-buffer

    const int tid  = threadIdx.x;
    const int lane = tid & 63;
    const int w    = tid >> 6;       // 0..7 -> m-slice (16 rows)
    const int l15  = lane & 15;
    const int lhi  = lane >> 4;      // 0..3

    const int b   = blockIdx.x;
    const int n0  = (b & 7) * 512;   // XCD b&7 owns this 256KB B-stripe (L2)
    const int m0  = (b >> 3) * 128;

    auto stageB = [&](int buf, int s) {
        const int sb = buf * 16384;
#pragma unroll
        for (int it = 0; it < 2; ++it) {
            const int o   = (it * 512 + tid) * 16;
            const int col = o >> 9;              // 0..31
            const int kb  = o & 511;
            const char* gb = Bt + (size_t)(n0 + s * 32 + col) * K_RED
                               + (kb ^ ((col & 7) << 4));
            __builtin_amdgcn_global_load_lds(
                (__attribute__((address_space(1))) void*)gb,
                (__attribute__((address_space(3))) void*)(smem + sb + o), 16, 0, 0);
        }
    };

    // Prologue: first B tile staging overlaps direct A-frag loads (xq is
    // LLC-resident, 4MB).
    stageB(0, 0);
    i32x4 af[8];
    {
        const char* ap = A + (size_t)(m0 + w * 16 + l15) * K_RED + lhi * 16;
#pragma unroll
        for (int ks = 0; ks < 8; ++ks)
            af[ks] = *reinterpret_cast<const i32x4*>(ap + ks * 64);
    }
    asm volatile("s_waitcnt vmcnt(0)" ::: "memory");
    __builtin_amdgcn_s_barrier();
    asm volatile("" ::: "memory");

    const int swz = (l15 & 7) << 4;

    for (int s = 0; s < NSTEPS; ++s) {
        const int buf = s & 1;
        if (s < NSTEPS - 1)
            stageB(buf ^ 1, s + 1);
        asm volatile("" ::: "memory");
        const int base = buf * 16384;
        const int b0 = base + l15 * 512;         // col l15
        const int b1 = base + (16 + l15) * 512;  // col 16+l15
        i32x4 acc0 = {}, acc1 = {};
#pragma unroll
        for (int g = 0; g < 2; ++g) {            // bf in 2 batches (VGPR)
            i32x4 bf0[4], bf1[4];
#pragma unroll
            for (int k4 = 0; k4 < 4; ++k4) {
                const int ko = ((g * 4 + k4) * 64 + lhi * 16) ^ swz;
                bf0[k4] = *reinterpret_cast<const i32x4*>(smem + b0 + ko);
                bf1[k4] = *reinterpret_cast<const i32x4*>(smem + b1 + ko);
            }
            __builtin_amdgcn_s_setprio(1);
#pragma unroll
            for (int k4 = 0; k4 < 4; ++k4) {
                const int ks = g * 4 + k4;
                // swapped operands: D[n][m] -> lane: m=l15, n=lhi*4+reg
                acc0 = __builtin_amdgcn_mfma_i32_16x16x64_i8(bf0[k4], af[ks], acc0, 0, 0, 0);
                acc1 = __builtin_amdgcn_mfma_i32_16x16x64_i8(bf1[k4], af[ks], acc1, 0, 0, 0);
            }
            __builtin_amdgcn_s_setprio(0);
        }
        // NT dwordx4 stores: lane l -> row m0+w*16+l15, cols cb+lhi*4 and
        // cb+16+lhi*4. One wave covers the full 128B line; NT keeps the
        // write-once C stream out of L2 so btq stays resident for stageB.
        const size_t row = (size_t)(m0 + w * 16 + l15);
        const int    cb  = n0 + s * 32;
        f32x4 v0, v1;
#pragma unroll
        for (int r = 0; r < 4; ++r) {
            v0[r] = (float)acc0[r] * 0.125f;
            v1[r] = (float)acc1[r] * 0.125f;
        }
        __builtin_nontemporal_store(v0,
            reinterpret_cast<f32x4*>(&C[row * N_TOT + cb + lhi * 4]));
        __builtin_nontemporal_store(v1,
            reinterpret_cast<f32x4*>(&C[row * N_TOT + cb + 16 + lhi * 4]));
        asm volatile("" ::: "memory");
        if (s < NSTEPS - 1) {
            // FIFO: [prev 2 stores][2 B-loads][2 stores]; vmcnt(2) retires
            // prev stores + loads; this step's stores keep flying.
            asm volatile("s_waitcnt vmcnt(2)" ::: "memory");
            __builtin_amdgcn_s_barrier();
            asm volatile("" ::: "memory");
        }
    }
}

// ---------------------------------------------------------------------------
extern "C" void kernel_launch(void* const* d_in, const int* in_sizes, int n_in,
                              void* d_out, int out_size, void* d_ws, size_t ws_size,
                              hipStream_t stream) {
    const float* x   = (const float*)d_in[0];       // [2,4096,4096] f32
    const int*   kin = (const int*)d_in[1];         // [2097152] int32 in {-1,0,1}
    float*       out = (float*)d_out;               // [2,4096,4096] f32

    char* xq  = (char*)d_ws;                                    // 4 MB
    char* btq = (char*)d_ws + (size_t)M_TOT * K_RED;            // 2 MB

    prep<<<dim3(4096 + 512), 256, 0, stream>>>(x, kin, xq, btq);
    gemm_as8<<<dim3(512), 512, 0, stream>>>(xq, btq, out);
}

// Round 17
// 55.959 us; speedup vs baseline: 1.1859x; 1.1859x over previous
//
#include <hip/hip_runtime.h>
#include <hip/hip_bf16.h>

// out[b,s,c] = x[b,s,:] @ W, W[r][c] = kernel[(r%512)*4096 + c]
// xr[m][r'] = sum_{i<8} x[m][r'+512i]  (M=8192, K'=512)
// INT8: xq = clamp(round(xr*8),-127,127); btq = kernel^T i8; out = acc*0.125f.
// Round 17: R11 exactly, except step-s columns = s*256 + (b&7)*32 (was
// (b&7)*512 + s*32). The 8 co-launched sibling blocks (same m-tile, XCDs
// 0..7) at the same step now write CONTIGUOUS 1KB per C row instead of 8
// scattered 128B pieces -> dense DRAM page coverage for the write stream.

#define M_TOT   8192
#define N_TOT   4096
#define K_RED   512
#define K_FULL  4096
#define NSTEPS  16

typedef __attribute__((ext_vector_type(4))) int   i32x4;
typedef __attribute__((ext_vector_type(4))) float f32x4;

// ---------------------------------------------------------------------------
// Prep (validated R5): blocks [0,4096): xq = i8 of 8-way reduced x (scale 8);
// blocks [4096,4608): btq[c][r'] = i8(kernel[r'*4096 + c]).
// ---------------------------------------------------------------------------
__global__ __launch_bounds__(256) void prep(const float* __restrict__ x,
                                            const int* __restrict__ kin,
                                            char* __restrict__ xq,
                                            char* __restrict__ btq) {
    __shared__ char tile[64][68];
    if (blockIdx.x < 4096) {
        const int row = blockIdx.x * 2 + (threadIdx.x >> 7);
        const int t2  = threadIdx.x & 127;
        const float* xp = x + (size_t)row * K_FULL + t2 * 4;
        float a0 = 0.f, a1 = 0.f, a2 = 0.f, a3 = 0.f;
#pragma unroll
        for (int i = 0; i < 8; ++i) {
            float4 v = *reinterpret_cast<const float4*>(xp + (size_t)i * K_RED);
            a0 += v.x; a1 += v.y; a2 += v.z; a3 += v.w;
        }
        int q0 = (int)rintf(a0 * 8.f), q1 = (int)rintf(a1 * 8.f);
        int q2 = (int)rintf(a2 * 8.f), q3 = (int)rintf(a3 * 8.f);
        q0 = min(127, max(-127, q0)); q1 = min(127, max(-127, q1));
        q2 = min(127, max(-127, q2)); q3 = min(127, max(-127, q3));
        int packed = (q0 & 0xFF) | ((q1 & 0xFF) << 8) | ((q2 & 0xFF) << 16)
                   | ((q3 & 0xFF) << 24);
        *reinterpret_cast<int*>(xq + (size_t)row * K_RED + t2 * 4) = packed;
    } else {
        const int b  = blockIdx.x - 4096;        // 0..511
        const int c0 = (b & 63) * 64;
        const int r0 = (b >> 6) * 64;
        const int tx = threadIdx.x & 63;
        const int ty = threadIdx.x >> 6;         // 0..3
#pragma unroll
        for (int rr = 0; rr < 64; rr += 4) {
            int r = r0 + rr + ty;
            tile[rr + ty][tx] = (char)kin[(size_t)r * N_TOT + c0 + tx];
        }
        __syncthreads();
        const int q  = tx & 15;                  // r'-quad (r' = q*4+j)
        const int ch = tx >> 4;                  // 0..3
#pragma unroll
        for (int i = 0; i < 4; ++i) {
            const int cl = i * 16 + ty * 4 + ch; // column offset 0..63
            int p = (tile[q * 4 + 0][cl] & 0xFF)
                  | ((tile[q * 4 + 1][cl] & 0xFF) << 8)
                  | ((tile[q * 4 + 2][cl] & 0xFF) << 16)
                  | ((tile[q * 4 + 3][cl] & 0xFF) << 24);
            *reinterpret_cast<int*>(btq + (size_t)(c0 + cl) * K_RED + r0 + q * 4) = p;
        }
    }
}

// ---------------------------------------------------------------------------
// A-resident streamed GEMM v9 (R11 + page-dense column mapping).
// Grid 512; block b: m0 = (b>>3)*128, step-s cols = s*256 + (b&7)*32.
// 512 thr = 8 waves; wave w owns rows w*16..+15, all 32 step cols.
// LDS = 2 x 16KB B dbuf; swizzle both sides: kb ^= (col&7)<<4.
// Swapped-operand D = mfma(bf, af): lane -> m=l15, n=lhi*4+reg.
// ---------------------------------------------------------------------------
__global__ __launch_bounds__(512, 4) void gemm_as9(const char* __restrict__ A,
                                                   const char* __restrict__ Bt,
                                                   float* __restrict__ C) {
    __shared__ char smem[32768];     // 2 x 16KB B double-buffer

    const int tid  = threadIdx.x;
    const int lane = tid & 63;
    const int w    = tid >> 6;       // 0..7 -> m-slice (16 rows)
    const int l15  = lane & 15;
    const int lhi  = lane >> 4;      // 0..3

    const int b    = blockIdx.x;
    const int xcd  = b & 7;          // co-launched siblings span XCDs 0..7
    const int m0   = (b >> 3) * 128;

    // step-s column base: siblings tile 8x32 = 256 contiguous cols per step
    auto colbase = [&](int s) { return s * 256 + xcd * 32; };

    auto stageB = [&](int buf, int s) {
        const int sb = buf * 16384;
        const int nc = colbase(s);
#pragma unroll
        for (int it = 0; it < 2; ++it) {
            const int o   = (it * 512 + tid) * 16;
            const int col = o >> 9;              // 0..31
            const int kb  = o & 511;
            const char* gb = Bt + (size_t)(nc + col) * K_RED
                               + (kb ^ ((col & 7) << 4));
            __builtin_amdgcn_global_load_lds(
                (__attribute__((address_space(1))) void*)gb,
                (__attribute__((address_space(3))) void*)(smem + sb + o), 16, 0, 0);
        }
    };

    // Prologue: first B tile staging overlaps direct A-frag loads.
    stageB(0, 0);
    i32x4 af[8];
    {
        const char* ap = A + (size_t)(m0 + w * 16 + l15) * K_RED + lhi * 16;
#pragma unroll
        for (int ks = 0; ks < 8; ++ks)
            af[ks] = *reinterpret_cast<const i32x4*>(ap + ks * 64);
    }
    asm volatile("s_waitcnt vmcnt(0)" ::: "memory");
    __builtin_amdgcn_s_barrier();
    asm volatile("" ::: "memory");

    const int swz = (l15 & 7) << 4;

    for (int s = 0; s < NSTEPS; ++s) {
        const int buf = s & 1;
        if (s < NSTEPS - 1)
            stageB(buf ^ 1, s + 1);
        asm volatile("" ::: "memory");
        const int base = buf * 16384;
        const int b0 = base + l15 * 512;         // col l15
        const int b1 = base + (16 + l15) * 512;  // col 16+l15
        i32x4 acc0 = {}, acc1 = {};
#pragma unroll
        for (int g = 0; g < 2; ++g) {            // bf in 2 batches (VGPR)
            i32x4 bf0[4], bf1[4];
#pragma unroll
            for (int k4 = 0; k4 < 4; ++k4) {
                const int ko = ((g * 4 + k4) * 64 + lhi * 16) ^ swz;
                bf0[k4] = *reinterpret_cast<const i32x4*>(smem + b0 + ko);
                bf1[k4] = *reinterpret_cast<const i32x4*>(smem + b1 + ko);
            }
            __builtin_amdgcn_s_setprio(1);
#pragma unroll
            for (int k4 = 0; k4 < 4; ++k4) {
                const int ks = g * 4 + k4;
                // swapped operands: D[n][m] -> lane: m=l15, n=lhi*4+reg
                acc0 = __builtin_amdgcn_mfma_i32_16x16x64_i8(bf0[k4], af[ks], acc0, 0, 0, 0);
                acc1 = __builtin_amdgcn_mfma_i32_16x16x64_i8(bf1[k4], af[ks], acc1, 0, 0, 0);
            }
            __builtin_amdgcn_s_setprio(0);
        }
        // dwordx4 stores: lane l -> row m0+w*16+l15, cols cb+lhi*4 and
        // cb+16+lhi*4. Wave-complete 128B lines; sibling blocks extend this
        // to contiguous 1KB per row at the same step.
        const size_t row = (size_t)(m0 + w * 16 + l15);
        const int    cb  = colbase(s);
        f32x4 v0, v1;
#pragma unroll
        for (int r = 0; r < 4; ++r) {
            v0[r] = (float)acc0[r] * 0.125f;
            v1[r] = (float)acc1[r] * 0.125f;
        }
        *reinterpret_cast<f32x4*>(&C[row * N_TOT + cb + lhi * 4])      = v0;
        *reinterpret_cast<f32x4*>(&C[row * N_TOT + cb + 16 + lhi * 4]) = v1;
        asm volatile("" ::: "memory");
        if (s < NSTEPS - 1) {
            // FIFO: [prev 2 stores][2 B-loads][2 stores]; vmcnt(2) retires
            // prev stores + loads; this step's stores keep flying.
            asm volatile("s_waitcnt vmcnt(2)" ::: "memory");
            __builtin_amdgcn_s_barrier();
            asm volatile("" ::: "memory");
        }
    }
}

// ---------------------------------------------------------------------------
extern "C" void kernel_launch(void* const* d_in, const int* in_sizes, int n_in,
                              void* d_out, int out_size, void* d_ws, size_t ws_size,
                              hipStream_t stream) {
    const float* x   = (const float*)d_in[0];       // [2,4096,4096] f32
    const int*   kin = (const int*)d_in[1];         // [2097152] int32 in {-1,0,1}
    float*       out = (float*)d_out;               // [2,4096,4096] f32

    char* xq  = (char*)d_ws;                                    // 4 MB
    char* btq = (char*)d_ws + (size_t)M_TOT * K_RED;            // 2 MB

    prep<<<dim3(4096 + 512), 256, 0, stream>>>(x, kin, xq, btq);
    gemm_as9<<<dim3(512), 512, 0, stream>>>(xq, btq, out);
}